// Round 14
// baseline (104.349 us; speedup 1.0000x reference)
//
#include <hip/hip_runtime.h>
#include <hip/hip_bf16.h>

#define N_NODES 8192
#define F_IN    512
#define F_HID   256
#define ALPHA   0.2f
#define MAXDEG  64

using f32x4 = __attribute__((ext_vector_type(4))) float;
using f16x8 = __attribute__((ext_vector_type(8))) _Float16;
using f16x4 = __attribute__((ext_vector_type(4))) _Float16;

// ---------------------------------------------------------------------------
// CSR row scan (device): one wave per adjacency row.
// ---------------------------------------------------------------------------
__device__ inline void csr_row(const float* __restrict__ adj, int* __restrict__ cols,
                               int* __restrict__ cnt, int row, int lane) {
    const f32x4* arow = (const f32x4*)(adj + (size_t)row * N_NODES);
    int* crow = cols + (size_t)row * MAXDEG;
    int count = 0;
    const unsigned long long mlt = (1ULL << lane) - 1ULL;
    for (int base = 0; base < N_NODES; base += 512) {
        f32x4 v0 = __builtin_nontemporal_load(&arow[(base >> 2) + lane]);
        f32x4 v1 = __builtin_nontemporal_load(&arow[(base >> 2) + 64 + lane]);
        unsigned long long b0 = __ballot(v0[0] > 0.0f);
        unsigned long long b1 = __ballot(v0[1] > 0.0f);
        unsigned long long b2 = __ballot(v0[2] > 0.0f);
        unsigned long long b3 = __ballot(v0[3] > 0.0f);
        unsigned long long b4 = __ballot(v1[0] > 0.0f);
        unsigned long long b5 = __ballot(v1[1] > 0.0f);
        unsigned long long b6 = __ballot(v1[2] > 0.0f);
        unsigned long long b7 = __ballot(v1[3] > 0.0f);
        int o = count + __popcll(b0 & mlt) + __popcll(b1 & mlt)
                      + __popcll(b2 & mlt) + __popcll(b3 & mlt);
        int c0 = base + (lane << 2);
        if (v0[0] > 0.0f) { if (o < MAXDEG) crow[o] = c0;     o++; }
        if (v0[1] > 0.0f) { if (o < MAXDEG) crow[o] = c0 + 1; o++; }
        if (v0[2] > 0.0f) { if (o < MAXDEG) crow[o] = c0 + 2; o++; }
        if (v0[3] > 0.0f) { if (o < MAXDEG) crow[o] = c0 + 3; o++; }
        count += __popcll(b0) + __popcll(b1) + __popcll(b2) + __popcll(b3);
        o = count + __popcll(b4 & mlt) + __popcll(b5 & mlt)
                  + __popcll(b6 & mlt) + __popcll(b7 & mlt);
        int c1 = base + 256 + (lane << 2);
        if (v1[0] > 0.0f) { if (o < MAXDEG) crow[o] = c1;     o++; }
        if (v1[1] > 0.0f) { if (o < MAXDEG) crow[o] = c1 + 1; o++; }
        if (v1[2] > 0.0f) { if (o < MAXDEG) crow[o] = c1 + 2; o++; }
        if (v1[3] > 0.0f) { if (o < MAXDEG) crow[o] = c1 + 3; o++; }
        count += __popcll(b4) + __popcll(b5) + __popcll(b6) + __popcll(b7);
    }
    if (lane == 0) cnt[row] = count > MAXDEG ? MAXDEG : count;
}

// ---------------------------------------------------------------------------
// GEMM1 tile (device): Wh1[64 x 128] fp16 = x(f32->f16) @ W1 col-tile.
// B staged directly from W1 (transpose-on-stage). Part-indexed s1/t1 writes.
// ---------------------------------------------------------------------------
__device__ inline void gemm1_tile(const float* __restrict__ x,
                                  const float* __restrict__ W1,
                                  _Float16* __restrict__ Wh1,
                                  const float* __restrict__ a1,
                                  float* __restrict__ s1p, float* __restrict__ t1p,
                                  int brow, int bcol) {
    const int LDT = 72;
    __shared__ _Float16 As[64 * LDT];
    __shared__ _Float16 Bs[128 * LDT];
    const int tid = threadIdx.x;
    const int wid = tid >> 6, lane = tid & 63;
    const int wr = (wid >> 1) * 32, wc = (wid & 1) * 64;
    const int sr = tid >> 3, skg = (tid & 7) * 8;

    f32x4 acc[2][4];
    #pragma unroll
    for (int m = 0; m < 2; ++m)
        #pragma unroll
        for (int n = 0; n < 4; ++n) acc[m][n] = f32x4{0.f, 0.f, 0.f, 0.f};

    for (int k0 = 0; k0 < F_IN; k0 += 64) {
        #pragma unroll
        for (int i = 0; i < 2; ++i) {
            int r = sr + i * 32;
            const f32x4* src = (const f32x4*)(x + (size_t)(brow + r) * F_IN + k0 + skg);
            f32x4 a0 = src[0];
            f32x4 a1v = src[1];
            f16x8 av;
            #pragma unroll
            for (int j = 0; j < 4; ++j) { av[j] = (_Float16)a0[j]; av[4 + j] = (_Float16)a1v[j]; }
            *(f16x8*)&As[r * LDT + skg] = av;
        }
        {
            const int cq = (tid & 31) * 4;
            const int kbase = tid >> 5;
            #pragma unroll
            for (int rd = 0; rd < 8; ++rd) {
                int krow = kbase + 8 * rd;
                f32x4 w = *(const f32x4*)&W1[(size_t)(k0 + krow) * F_HID + bcol + cq];
                #pragma unroll
                for (int q = 0; q < 4; ++q)
                    Bs[(cq + q) * LDT + krow] = (_Float16)w[q];
            }
        }
        __syncthreads();
        #pragma unroll
        for (int ks = 0; ks < 2; ++ks) {
            const int kb = ks * 32 + (lane >> 4) * 8;
            f16x8 af[2], bfr[4];
            #pragma unroll
            for (int m = 0; m < 2; ++m)
                af[m] = *(const f16x8*)&As[(wr + m * 16 + (lane & 15)) * LDT + kb];
            #pragma unroll
            for (int n = 0; n < 4; ++n)
                bfr[n] = *(const f16x8*)&Bs[(wc + n * 16 + (lane & 15)) * LDT + kb];
            #pragma unroll
            for (int m = 0; m < 2; ++m)
                #pragma unroll
                for (int n = 0; n < 4; ++n)
                    acc[m][n] = __builtin_amdgcn_mfma_f32_16x16x32_f16(
                        af[m], bfr[n], acc[m][n], 0, 0, 0);
        }
        __syncthreads();
    }
    const int cl = lane & 15;
    const int part = (bcol >> 7) * 2 + (wc >> 6);
    float as[4], at[4];
    #pragma unroll
    for (int n = 0; n < 4; ++n) {
        as[n] = a1[bcol + wc + n * 16 + cl];
        at[n] = a1[F_HID + bcol + wc + n * 16 + cl];
    }
    #pragma unroll
    for (int m = 0; m < 2; ++m) {
        #pragma unroll
        for (int j = 0; j < 4; ++j) {
            float vs = 0.f, vt = 0.f;
            #pragma unroll
            for (int n = 0; n < 4; ++n) { vs += acc[m][n][j] * as[n]; vt += acc[m][n][j] * at[n]; }
            #pragma unroll
            for (int off = 1; off < 16; off <<= 1) {
                vs += __shfl_xor(vs, off);
                vt += __shfl_xor(vt, off);
            }
            if (cl == 0) {
                int row = brow + wr + m * 16 + ((lane >> 4) << 2) + j;
                s1p[part * N_NODES + row] = vs;
                t1p[part * N_NODES + row] = vt;
            }
        }
        #pragma unroll
        for (int n = 0; n < 4; ++n) {
            int row = brow + wr + m * 16 + ((lane >> 4) << 2);
            int col = bcol + wc + n * 16 + cl;
            #pragma unroll
            for (int j = 0; j < 4; ++j)
                Wh1[(size_t)(row + j) * F_HID + col] = (_Float16)acc[m][n][j];
        }
    }
}

// ---------------------------------------------------------------------------
// W2 transpose tile (32x32) + w2s/w2t jobs (prep, runs inside kernel A).
// ---------------------------------------------------------------------------
__device__ inline void w2T_tile(int t, const float* __restrict__ W2,
                                _Float16* __restrict__ W2T) {
    __shared__ float Ws[32][33];
    const int kt = t & 7, nt = t >> 3;
    const int tx = threadIdx.x & 31, ty = threadIdx.x >> 5;
    #pragma unroll
    for (int i = 0; i < 4; ++i)
        Ws[ty + 8 * i][tx] = W2[(size_t)(kt * 32 + ty + 8 * i) * F_IN + nt * 32 + tx];
    __syncthreads();
    #pragma unroll
    for (int i = 0; i < 4; ++i)
        W2T[(size_t)(nt * 32 + ty + 8 * i) * F_HID + kt * 32 + tx] = (_Float16)Ws[tx][ty + 8 * i];
}

__device__ inline void w2vec_job(int t, const float* __restrict__ W2,
                                 const float* __restrict__ a2,
                                 float* __restrict__ w2s, float* __restrict__ w2t) {
    const int r = t * 64 + (threadIdx.x >> 2);
    const int q = threadIdx.x & 3;
    float ss = 0.f, tt = 0.f;
    for (int n = q * 4; n < F_IN; n += 16) {
        f32x4 w  = *(const f32x4*)&W2[(size_t)r * F_IN + n];
        f32x4 as = *(const f32x4*)&a2[n];
        f32x4 at = *(const f32x4*)&a2[F_IN + n];
        #pragma unroll
        for (int j = 0; j < 4; ++j) { ss += w[j] * as[j]; tt += w[j] * at[j]; }
    }
    ss += __shfl_xor(ss, 1); ss += __shfl_xor(ss, 2);
    tt += __shfl_xor(tt, 1); tt += __shfl_xor(tt, 2);
    if (q == 0) { w2s[r] = ss; w2t[r] = tt; }
}

// ---------------------------------------------------------------------------
// Kernel A: gemm1 (256, low bids) + W2T/w2vec prep (132) + csr ALL rows.
// (R12-proven partition: full csr stream shadows gemm1.)
// ---------------------------------------------------------------------------
__global__ __launch_bounds__(256)
void front_kernel(const float* __restrict__ adj, int* __restrict__ cols,
                  int* __restrict__ cnt, const float* __restrict__ x,
                  const float* __restrict__ W1, const float* __restrict__ a1,
                  _Float16* __restrict__ Wh1,
                  float* __restrict__ s1p, float* __restrict__ t1p,
                  const float* __restrict__ W2, const float* __restrict__ a2,
                  _Float16* __restrict__ W2T,
                  float* __restrict__ w2s, float* __restrict__ w2t) {
    const int bid = blockIdx.x;
    if (bid < 256) {
        gemm1_tile(x, W1, Wh1, a1, s1p, t1p, (bid & 127) * 64, (bid >> 7) * 128);
    } else if (bid < 384) {
        w2T_tile(bid - 256, W2, W2T);
    } else if (bid < 388) {
        w2vec_job(bid - 384, W2, a2, w2s, w2t);
    } else {
        const int q = bid - 388;                        // quad in [0, 2048)
        const int row = q * 4 + (threadIdx.x >> 6);
        csr_row(adj, cols, cnt, row, threadIdx.x & 63);
    }
}

// ---------------------------------------------------------------------------
// Kernel B: layer-1 aggregate (R12 exact): softmax(s1,t1 from 4 parts),
// gather Wh1 fp16, ELU, write enc f32 (NT) + enc16; epilogue s2/t2.
// ---------------------------------------------------------------------------
__global__ __launch_bounds__(256)
void aggregate_l1(const _Float16* __restrict__ Wh,
                  const int* __restrict__ cols, const int* __restrict__ cnt,
                  const float* __restrict__ s1p, const float* __restrict__ t1p,
                  const float* __restrict__ w2s, const float* __restrict__ w2t,
                  float* __restrict__ enc, _Float16* __restrict__ enc16,
                  float* __restrict__ s2, float* __restrict__ t2) {
    const int wid = threadIdx.x >> 6, lane = threadIdx.x & 63;
    const int row = blockIdx.x * 4 + wid;
    const int deg = cnt[row];
    __shared__ float pS[4][64];
    __shared__ int jS[4][64];
    const float sI = s1p[row] + s1p[N_NODES + row]
                   + s1p[2 * N_NODES + row] + s1p[3 * N_NODES + row];
    int j = 0;
    float ev = -1e30f;
    if (lane < deg) {
        j = cols[(size_t)row * MAXDEG + lane];
        float tj = t1p[j] + t1p[N_NODES + j]
                 + t1p[2 * N_NODES + j] + t1p[3 * N_NODES + j];
        float z = sI + tj;
        ev = z > 0.0f ? z : ALPHA * z;
    }
    float m = ev;
    #pragma unroll
    for (int off = 32; off > 0; off >>= 1) m = fmaxf(m, __shfl_xor(m, off));
    float ex = (lane < deg) ? __expf(ev - m) : 0.0f;
    float sum = ex;
    #pragma unroll
    for (int off = 32; off > 0; off >>= 1) sum += __shfl_xor(sum, off);
    pS[wid][lane] = ex / sum;
    jS[wid][lane] = j;
    __syncthreads();

    float acc[4] = {};
    const size_t lo = (size_t)lane * 4;
    int d = 0;
    for (; d + 4 <= deg; d += 4) {
        float p0 = pS[wid][d],     p1 = pS[wid][d + 1];
        float p2 = pS[wid][d + 2], p3 = pS[wid][d + 3];
        f16x4 v0 = *(const f16x4*)(Wh + (size_t)jS[wid][d] * F_HID + lo);
        f16x4 v1 = *(const f16x4*)(Wh + (size_t)jS[wid][d + 1] * F_HID + lo);
        f16x4 v2 = *(const f16x4*)(Wh + (size_t)jS[wid][d + 2] * F_HID + lo);
        f16x4 v3 = *(const f16x4*)(Wh + (size_t)jS[wid][d + 3] * F_HID + lo);
        #pragma unroll
        for (int jj = 0; jj < 4; ++jj)
            acc[jj] += p0 * (float)v0[jj] + p1 * (float)v1[jj]
                     + p2 * (float)v2[jj] + p3 * (float)v3[jj];
    }
    for (; d < deg; ++d) {
        float p = pS[wid][d];
        f16x4 w = *(const f16x4*)(Wh + (size_t)jS[wid][d] * F_HID + lo);
        #pragma unroll
        for (int jj = 0; jj < 4; ++jj) acc[jj] += p * (float)w[jj];
    }
    f32x4 o; f16x4 h;
    #pragma unroll
    for (int jj = 0; jj < 4; ++jj) {
        float v = acc[jj];
        float e = v > 0.0f ? v : (__expf(v) - 1.0f);
        o[jj] = e; h[jj] = (_Float16)e;
    }
    __builtin_nontemporal_store(o, (f32x4*)(enc + (size_t)row * F_HID + lo));
    *(f16x4*)(enc16 + (size_t)row * F_HID + lo) = h;

    f32x4 ws = *(const f32x4*)(w2s + lo);
    f32x4 wt = *(const f32x4*)(w2t + lo);
    float ps = 0.f, pt = 0.f;
    #pragma unroll
    for (int jj = 0; jj < 4; ++jj) { ps += o[jj] * ws[jj]; pt += o[jj] * wt[jj]; }
    #pragma unroll
    for (int off = 32; off > 0; off >>= 1) {
        ps += __shfl_xor(ps, off);
        pt += __shfl_xor(pt, off);
    }
    if (lane == 0) { s2[row] = ps; t2[row] = pt; }
}

// ---------------------------------------------------------------------------
// Layer-2 pre-aggregate quad (device): softmax(s2,t2), gather enc16,
// write aggE16. Per-wave LDS slices only (no block barrier needed).
// ---------------------------------------------------------------------------
__device__ inline void agg_l2_quad(int q, const _Float16* __restrict__ enc16,
                                   const int* __restrict__ cols, const int* __restrict__ cnt,
                                   const float* __restrict__ s, const float* __restrict__ t,
                                   _Float16* __restrict__ aggE16,
                                   float (*pS)[64], int (*jS)[64]) {
    const int wid = threadIdx.x >> 6, lane = threadIdx.x & 63;
    const int row = q * 4 + wid;
    const int deg = cnt[row];
    int j = 0;
    float ev = -1e30f;
    if (lane < deg) {
        j = cols[(size_t)row * MAXDEG + lane];
        float z = s[row] + t[j];
        ev = z > 0.0f ? z : ALPHA * z;
    }
    float m = ev;
    #pragma unroll
    for (int off = 32; off > 0; off >>= 1) m = fmaxf(m, __shfl_xor(m, off));
    float ex = (lane < deg) ? __expf(ev - m) : 0.0f;
    float sum = ex;
    #pragma unroll
    for (int off = 32; off > 0; off >>= 1) sum += __shfl_xor(sum, off);
    pS[wid][lane] = ex / sum;
    jS[wid][lane] = j;

    float acc[4] = {};
    const size_t lo = (size_t)lane * 4;
    int d = 0;
    for (; d + 4 <= deg; d += 4) {
        float p0 = pS[wid][d],     p1 = pS[wid][d + 1];
        float p2 = pS[wid][d + 2], p3 = pS[wid][d + 3];
        f16x4 v0 = *(const f16x4*)(enc16 + (size_t)jS[wid][d] * F_HID + lo);
        f16x4 v1 = *(const f16x4*)(enc16 + (size_t)jS[wid][d + 1] * F_HID + lo);
        f16x4 v2 = *(const f16x4*)(enc16 + (size_t)jS[wid][d + 2] * F_HID + lo);
        f16x4 v3 = *(const f16x4*)(enc16 + (size_t)jS[wid][d + 3] * F_HID + lo);
        #pragma unroll
        for (int jj = 0; jj < 4; ++jj)
            acc[jj] += p0 * (float)v0[jj] + p1 * (float)v1[jj]
                     + p2 * (float)v2[jj] + p3 * (float)v3[jj];
    }
    for (; d < deg; ++d) {
        float p = pS[wid][d];
        f16x4 w = *(const f16x4*)(enc16 + (size_t)jS[wid][d] * F_HID + lo);
        #pragma unroll
        for (int jj = 0; jj < 4; ++jj) acc[jj] += p * (float)w[jj];
    }
    f16x4 h;
    #pragma unroll
    for (int jj = 0; jj < 4; ++jj) h[jj] = (_Float16)acc[jj];
    *(f16x4*)(aggE16 + (size_t)row * F_HID + lo) = h;
}

// ---------------------------------------------------------------------------
// GEMM2e tile (device): dec[128 x 64] f32 = elu( aggE16 @ W2 ). BM=128 BN=64,
// B panel staged once per block; NT f32 stores. smem passed in.
// ---------------------------------------------------------------------------
__device__ inline void gemm2e_tile(int tile, const _Float16* __restrict__ A,
                                   const _Float16* __restrict__ BT,
                                   float* __restrict__ C,
                                   _Float16* As, _Float16* Bs) {
    const int LDT = 72, LDB = 264;
    const int tid = threadIdx.x;
    const int wid = tid >> 6, lane = tid & 63;
    const int brow = (tile >> 3) * 128;
    const int bcol = (tile & 7) * 64;
    const int wr = (wid >> 1) * 64, wc = (wid & 1) * 32;

    #pragma unroll
    for (int i = 0; i < 8; ++i) {
        int id = tid + i * 256;
        int r = id >> 5, kc = (id & 31) * 8;
        *(f16x8*)&Bs[r * LDB + kc] = *(const f16x8*)&BT[(size_t)(bcol + r) * F_HID + kc];
    }

    f32x4 acc[4][2];
    #pragma unroll
    for (int m = 0; m < 4; ++m)
        #pragma unroll
        for (int n = 0; n < 2; ++n) acc[m][n] = f32x4{0.f, 0.f, 0.f, 0.f};

    for (int k0 = 0; k0 < F_HID; k0 += 64) {
        #pragma unroll
        for (int i = 0; i < 4; ++i) {
            int id = tid + i * 256;
            int r = id >> 3, kc = (id & 7) * 8;
            *(f16x8*)&As[r * LDT + kc] = *(const f16x8*)&A[(size_t)(brow + r) * F_HID + k0 + kc];
        }
        __syncthreads();
        #pragma unroll
        for (int ks = 0; ks < 2; ++ks) {
            const int kb = ks * 32 + (lane >> 4) * 8;
            f16x8 af[4], bfr[2];
            #pragma unroll
            for (int m = 0; m < 4; ++m)
                af[m] = *(const f16x8*)&As[(wr + m * 16 + (lane & 15)) * LDT + kb];
            #pragma unroll
            for (int n = 0; n < 2; ++n)
                bfr[n] = *(const f16x8*)&Bs[(wc + n * 16 + (lane & 15)) * LDB + k0 + kb];
            #pragma unroll
            for (int m = 0; m < 4; ++m)
                #pragma unroll
                for (int n = 0; n < 2; ++n)
                    acc[m][n] = __builtin_amdgcn_mfma_f32_16x16x32_f16(
                        af[m], bfr[n], acc[m][n], 0, 0, 0);
        }
        __syncthreads();
    }
    #pragma unroll
    for (int m = 0; m < 4; ++m)
        #pragma unroll
        for (int n = 0; n < 2; ++n) {
            int row = brow + wr + m * 16 + ((lane >> 4) << 2);
            int col = bcol + wc + n * 16 + (lane & 15);
            #pragma unroll
            for (int j = 0; j < 4; ++j) {
                float v = acc[m][n][j];
                float e = v > 0.0f ? v : (__expf(v) - 1.0f);
                __builtin_nontemporal_store(e, &C[(size_t)(row + j) * F_IN + col]);
            }
        }
}

// ---------------------------------------------------------------------------
// Kernel C1: agg_l2pre quads 0..1023 (rows 0..4095).
// ---------------------------------------------------------------------------
__global__ __launch_bounds__(256)
void agg2_first(const _Float16* __restrict__ enc16,
                const int* __restrict__ cols, const int* __restrict__ cnt,
                const float* __restrict__ s2, const float* __restrict__ t2,
                _Float16* __restrict__ aggE16) {
    __shared__ float pS[4][64];
    __shared__ int jS[4][64];
    agg_l2_quad(blockIdx.x, enc16, cols, cnt, s2, t2, aggE16, pS, jS);
}

// ---------------------------------------------------------------------------
// Kernel CD: gemm2e tiles 0..255 (rows 0..4095, MFMA-bound, low bids)
// IN PARALLEL with agg_l2pre quads 1024..2047 (L2-gather-bound).
// Separate blocks, disjoint resources.
// ---------------------------------------------------------------------------
__global__ __launch_bounds__(256)
void cd_kernel(const _Float16* __restrict__ enc16, const _Float16* __restrict__ W2T,
               const int* __restrict__ cols, const int* __restrict__ cnt,
               const float* __restrict__ s2, const float* __restrict__ t2,
               _Float16* __restrict__ aggE16, float* __restrict__ dec) {
    __shared__ __align__(16) char smem[128 * 72 * 2 + 64 * 264 * 2];  // 52.2 KB
    const int bid = blockIdx.x;
    if (bid < 256) {
        _Float16* As = (_Float16*)smem;
        _Float16* Bs = (_Float16*)(smem + 128 * 72 * 2);
        gemm2e_tile(bid, aggE16, W2T, dec, As, Bs);
    } else {
        float (*pS)[64] = (float(*)[64])smem;
        int (*jS)[64] = (int(*)[64])(smem + 1024);
        agg_l2_quad(1024 + (bid - 256), enc16, cols, cnt, s2, t2, aggE16, pS, jS);
    }
}

// ---------------------------------------------------------------------------
// Kernel D2: gemm2e tiles 256..511 (rows 4096..8191).
// ---------------------------------------------------------------------------
__global__ __launch_bounds__(256)
void gemm2_rest(const _Float16* __restrict__ aggE16, const _Float16* __restrict__ W2T,
                float* __restrict__ dec) {
    __shared__ __align__(16) _Float16 As[128 * 72];
    __shared__ __align__(16) _Float16 Bs[64 * 264];
    gemm2e_tile(256 + blockIdx.x, aggE16, W2T, dec, As, Bs);
}

// ---------------------------------------------------------------------------
extern "C" void kernel_launch(void* const* d_in, const int* in_sizes, int n_in,
                              void* d_out, int out_size, void* d_ws, size_t ws_size,
                              hipStream_t stream) {
    (void)in_sizes; (void)n_in; (void)out_size; (void)ws_size;
    const float* x   = (const float*)d_in[0];
    const float* adj = (const float*)d_in[1];
    const float* W1  = (const float*)d_in[2];
    const float* a1  = (const float*)d_in[3];
    const float* W2  = (const float*)d_in[4];
    const float* a2  = (const float*)d_in[5];

    float* dec = (float*)d_out;                           // [8192, 512] f32
    float* enc = dec + (size_t)N_NODES * F_IN;            // [8192, 256] f32

    int*      cols   = (int*)d_ws;                        // 8192*64
    int*      cnt    = cols + (size_t)N_NODES * MAXDEG;   // 8192
    float*    s1p    = (float*)(cnt + N_NODES);           // 4*8192 (parts)
    float*    t1p    = s1p + 4 * N_NODES;                 // 4*8192 (parts)
    float*    s2     = t1p + 4 * N_NODES;                 // 8192
    float*    t2     = s2 + N_NODES;                      // 8192
    float*    w2s    = t2 + N_NODES;                      // 256
    float*    w2t    = w2s + F_HID;                       // 256
    _Float16* Wh1    = (_Float16*)(w2t + F_HID);          // 8192*256 fp16
    _Float16* enc16  = Wh1 + (size_t)N_NODES * F_HID;     // 8192*256 fp16
    _Float16* aggE16 = enc16 + (size_t)N_NODES * F_HID;   // 8192*256 fp16
    _Float16* W2T    = aggE16 + (size_t)N_NODES * F_HID;  // 512*256 fp16

    // A. csr (all rows) || gemm1 (direct-W1 staging) || W2T/w2vec prep
    front_kernel<<<2436, 256, 0, stream>>>(adj, cols, cnt, x, W1, a1, Wh1,
                                           s1p, t1p, W2, a2, W2T, w2s, w2t);

    // B. layer-1 attention -> enc, enc16; epilogue s2/t2
    aggregate_l1<<<N_NODES / 4, 256, 0, stream>>>(Wh1, cols, cnt, s1p, t1p,
                                                  w2s, w2t, enc, enc16, s2, t2);

    // C1. agg_l2pre rows 0..4095
    agg2_first<<<1024, 256, 0, stream>>>(enc16, cols, cnt, s2, t2, aggE16);

    // CD. gemm2e rows 0..4095 (MFMA) || agg_l2pre rows 4096..8191 (L2 gather)
    cd_kernel<<<1280, 256, 0, stream>>>(enc16, W2T, cols, cnt, s2, t2, aggE16, dec);

    // D2. gemm2e rows 4096..8191
    gemm2_rest<<<256, 256, 0, stream>>>(aggE16, W2T, dec);
}

// Round 15
// 98.957 us; speedup vs baseline: 1.0545x; 1.0545x over previous
//
#include <hip/hip_runtime.h>
#include <hip/hip_bf16.h>

#define N_NODES 8192
#define F_IN    512
#define F_HID   256
#define ALPHA   0.2f
#define MAXDEG  64

using f32x4 = __attribute__((ext_vector_type(4))) float;
using f16x8 = __attribute__((ext_vector_type(8))) _Float16;
using f16x4 = __attribute__((ext_vector_type(4))) _Float16;

// ---------------------------------------------------------------------------
// CSR row scan (device): one wave per adjacency row.
// ---------------------------------------------------------------------------
__device__ inline void csr_row(const float* __restrict__ adj, int* __restrict__ cols,
                               int* __restrict__ cnt, int row, int lane) {
    const f32x4* arow = (const f32x4*)(adj + (size_t)row * N_NODES);
    int* crow = cols + (size_t)row * MAXDEG;
    int count = 0;
    const unsigned long long mlt = (1ULL << lane) - 1ULL;
    for (int base = 0; base < N_NODES; base += 512) {
        f32x4 v0 = __builtin_nontemporal_load(&arow[(base >> 2) + lane]);
        f32x4 v1 = __builtin_nontemporal_load(&arow[(base >> 2) + 64 + lane]);
        unsigned long long b0 = __ballot(v0[0] > 0.0f);
        unsigned long long b1 = __ballot(v0[1] > 0.0f);
        unsigned long long b2 = __ballot(v0[2] > 0.0f);
        unsigned long long b3 = __ballot(v0[3] > 0.0f);
        unsigned long long b4 = __ballot(v1[0] > 0.0f);
        unsigned long long b5 = __ballot(v1[1] > 0.0f);
        unsigned long long b6 = __ballot(v1[2] > 0.0f);
        unsigned long long b7 = __ballot(v1[3] > 0.0f);
        int o = count + __popcll(b0 & mlt) + __popcll(b1 & mlt)
                      + __popcll(b2 & mlt) + __popcll(b3 & mlt);
        int c0 = base + (lane << 2);
        if (v0[0] > 0.0f) { if (o < MAXDEG) crow[o] = c0;     o++; }
        if (v0[1] > 0.0f) { if (o < MAXDEG) crow[o] = c0 + 1; o++; }
        if (v0[2] > 0.0f) { if (o < MAXDEG) crow[o] = c0 + 2; o++; }
        if (v0[3] > 0.0f) { if (o < MAXDEG) crow[o] = c0 + 3; o++; }
        count += __popcll(b0) + __popcll(b1) + __popcll(b2) + __popcll(b3);
        o = count + __popcll(b4 & mlt) + __popcll(b5 & mlt)
                  + __popcll(b6 & mlt) + __popcll(b7 & mlt);
        int c1 = base + 256 + (lane << 2);
        if (v1[0] > 0.0f) { if (o < MAXDEG) crow[o] = c1;     o++; }
        if (v1[1] > 0.0f) { if (o < MAXDEG) crow[o] = c1 + 1; o++; }
        if (v1[2] > 0.0f) { if (o < MAXDEG) crow[o] = c1 + 2; o++; }
        if (v1[3] > 0.0f) { if (o < MAXDEG) crow[o] = c1 + 3; o++; }
        count += __popcll(b4) + __popcll(b5) + __popcll(b6) + __popcll(b7);
    }
    if (lane == 0) cnt[row] = count > MAXDEG ? MAXDEG : count;
}

// ---------------------------------------------------------------------------
// GEMM1 tile (device): Wh1[64 x 128] fp16 = x(f32->f16) @ W1 col-tile.
// B staged DIRECTLY from W1 (f32, transpose-on-stage) -> no W1T prep needed.
// BM=64, BN=128, BK=64; 4 waves (2m x 2n). Epilogue: part-indexed s1/t1
// writes (no atomics, no zeroing): part = (bcol>>7)*2 + (wc>>6).
// ---------------------------------------------------------------------------
__device__ inline void gemm1_tile(const float* __restrict__ x,
                                  const float* __restrict__ W1,
                                  _Float16* __restrict__ Wh1,
                                  const float* __restrict__ a1,
                                  float* __restrict__ s1p, float* __restrict__ t1p,
                                  int brow, int bcol) {
    const int LDT = 72;
    __shared__ _Float16 As[64 * LDT];
    __shared__ _Float16 Bs[128 * LDT];
    const int tid = threadIdx.x;
    const int wid = tid >> 6, lane = tid & 63;
    const int wr = (wid >> 1) * 32, wc = (wid & 1) * 64;
    const int sr = tid >> 3, skg = (tid & 7) * 8;

    f32x4 acc[2][4];
    #pragma unroll
    for (int m = 0; m < 2; ++m)
        #pragma unroll
        for (int n = 0; n < 4; ++n) acc[m][n] = f32x4{0.f, 0.f, 0.f, 0.f};

    for (int k0 = 0; k0 < F_IN; k0 += 64) {
        // stage A (x -> fp16)
        #pragma unroll
        for (int i = 0; i < 2; ++i) {
            int r = sr + i * 32;
            const f32x4* src = (const f32x4*)(x + (size_t)(brow + r) * F_IN + k0 + skg);
            f32x4 a0 = src[0];
            f32x4 a1v = src[1];
            f16x8 av;
            #pragma unroll
            for (int j = 0; j < 4; ++j) { av[j] = (_Float16)a0[j]; av[4 + j] = (_Float16)a1v[j]; }
            *(f16x8*)&As[r * LDT + skg] = av;
        }
        // stage B directly from W1 [512][256] (transpose-on-stage)
        {
            const int cq = (tid & 31) * 4;           // col quad within tile
            const int kbase = tid >> 5;              // 8 k rows per round
            #pragma unroll
            for (int rd = 0; rd < 8; ++rd) {
                int krow = kbase + 8 * rd;
                f32x4 w = *(const f32x4*)&W1[(size_t)(k0 + krow) * F_HID + bcol + cq];
                #pragma unroll
                for (int q = 0; q < 4; ++q)
                    Bs[(cq + q) * LDT + krow] = (_Float16)w[q];
            }
        }
        __syncthreads();
        #pragma unroll
        for (int ks = 0; ks < 2; ++ks) {
            const int kb = ks * 32 + (lane >> 4) * 8;
            f16x8 af[2], bfr[4];
            #pragma unroll
            for (int m = 0; m < 2; ++m)
                af[m] = *(const f16x8*)&As[(wr + m * 16 + (lane & 15)) * LDT + kb];
            #pragma unroll
            for (int n = 0; n < 4; ++n)
                bfr[n] = *(const f16x8*)&Bs[(wc + n * 16 + (lane & 15)) * LDT + kb];
            #pragma unroll
            for (int m = 0; m < 2; ++m)
                #pragma unroll
                for (int n = 0; n < 4; ++n)
                    acc[m][n] = __builtin_amdgcn_mfma_f32_16x16x32_f16(
                        af[m], bfr[n], acc[m][n], 0, 0, 0);
        }
        __syncthreads();
    }
    const int cl = lane & 15;
    const int part = (bcol >> 7) * 2 + (wc >> 6);
    float as[4], at[4];
    #pragma unroll
    for (int n = 0; n < 4; ++n) {
        as[n] = a1[bcol + wc + n * 16 + cl];
        at[n] = a1[F_HID + bcol + wc + n * 16 + cl];
    }
    #pragma unroll
    for (int m = 0; m < 2; ++m) {
        #pragma unroll
        for (int j = 0; j < 4; ++j) {
            float vs = 0.f, vt = 0.f;
            #pragma unroll
            for (int n = 0; n < 4; ++n) { vs += acc[m][n][j] * as[n]; vt += acc[m][n][j] * at[n]; }
            #pragma unroll
            for (int off = 1; off < 16; off <<= 1) {
                vs += __shfl_xor(vs, off);
                vt += __shfl_xor(vt, off);
            }
            if (cl == 0) {
                int row = brow + wr + m * 16 + ((lane >> 4) << 2) + j;
                s1p[part * N_NODES + row] = vs;
                t1p[part * N_NODES + row] = vt;
            }
        }
        #pragma unroll
        for (int n = 0; n < 4; ++n) {
            int row = brow + wr + m * 16 + ((lane >> 4) << 2);
            int col = bcol + wc + n * 16 + cl;
            #pragma unroll
            for (int j = 0; j < 4; ++j)
                Wh1[(size_t)(row + j) * F_HID + col] = (_Float16)acc[m][n][j];
        }
    }
}

// ---------------------------------------------------------------------------
// W2 transpose tile job (32x32): W2 [256][512] f32 -> W2T [512][256] fp16.
// ---------------------------------------------------------------------------
__device__ inline void w2T_tile(int t, const float* __restrict__ W2,
                                _Float16* __restrict__ W2T) {
    __shared__ float Ws[32][33];
    const int kt = t & 7, nt = t >> 3;   // k-tile of 256, n-tile of 512
    const int tx = threadIdx.x & 31, ty = threadIdx.x >> 5;  // 32 x 8
    #pragma unroll
    for (int i = 0; i < 4; ++i)
        Ws[ty + 8 * i][tx] = W2[(size_t)(kt * 32 + ty + 8 * i) * F_IN + nt * 32 + tx];
    __syncthreads();
    #pragma unroll
    for (int i = 0; i < 4; ++i)
        W2T[(size_t)(nt * 32 + ty + 8 * i) * F_HID + kt * 32 + tx] = (_Float16)Ws[tx][ty + 8 * i];
}

// ---------------------------------------------------------------------------
// w2s/w2t job: w2s[k] = W2[k,:] . a2[0:512], w2t[k] = W2[k,:] . a2[512:].
// ---------------------------------------------------------------------------
__device__ inline void w2vec_job(int t, const float* __restrict__ W2,
                                 const float* __restrict__ a2,
                                 float* __restrict__ w2s, float* __restrict__ w2t) {
    const int r = t * 64 + (threadIdx.x >> 2);
    const int q = threadIdx.x & 3;
    float ss = 0.f, tt = 0.f;
    for (int n = q * 4; n < F_IN; n += 16) {
        f32x4 w  = *(const f32x4*)&W2[(size_t)r * F_IN + n];
        f32x4 as = *(const f32x4*)&a2[n];
        f32x4 at = *(const f32x4*)&a2[F_IN + n];
        #pragma unroll
        for (int j = 0; j < 4; ++j) { ss += w[j] * as[j]; tt += w[j] * at[j]; }
    }
    ss += __shfl_xor(ss, 1); ss += __shfl_xor(ss, 2);
    tt += __shfl_xor(tt, 1); tt += __shfl_xor(tt, 2);
    if (q == 0) { w2s[r] = ss; w2t[r] = tt; }
}

// ---------------------------------------------------------------------------
// Kernel A: gemm1 (256 jobs, low bids) + W2T/w2vec prep (132) + csr (2048).
// ---------------------------------------------------------------------------
__global__ __launch_bounds__(256)
void front_kernel(const float* __restrict__ adj, int* __restrict__ cols,
                  int* __restrict__ cnt, const float* __restrict__ x,
                  const float* __restrict__ W1, const float* __restrict__ a1,
                  _Float16* __restrict__ Wh1,
                  float* __restrict__ s1p, float* __restrict__ t1p,
                  const float* __restrict__ W2, const float* __restrict__ a2,
                  _Float16* __restrict__ W2T,
                  float* __restrict__ w2s, float* __restrict__ w2t) {
    const int bid = blockIdx.x;
    if (bid < 256) {
        gemm1_tile(x, W1, Wh1, a1, s1p, t1p, (bid & 127) * 64, (bid >> 7) * 128);
    } else if (bid < 384) {
        w2T_tile(bid - 256, W2, W2T);
    } else if (bid < 388) {
        w2vec_job(bid - 384, W2, a2, w2s, w2t);
    } else {
        const int q = bid - 388;                        // quad in [0, 2048)
        const int row = q * 4 + (threadIdx.x >> 6);
        csr_row(adj, cols, cnt, row, threadIdx.x & 63);
    }
}

// ---------------------------------------------------------------------------
// Kernel B: layer-1 aggregate (R9 structure): softmax(s1,t1 from 4 parts),
// gather Wh1 fp16, ELU, write enc f32 (NT) + enc16; epilogue s2/t2.
// ---------------------------------------------------------------------------
__global__ __launch_bounds__(256)
void aggregate_l1(const _Float16* __restrict__ Wh,
                  const int* __restrict__ cols, const int* __restrict__ cnt,
                  const float* __restrict__ s1p, const float* __restrict__ t1p,
                  const float* __restrict__ w2s, const float* __restrict__ w2t,
                  float* __restrict__ enc, _Float16* __restrict__ enc16,
                  float* __restrict__ s2, float* __restrict__ t2) {
    const int wid = threadIdx.x >> 6, lane = threadIdx.x & 63;
    const int row = blockIdx.x * 4 + wid;
    const int deg = cnt[row];
    __shared__ float pS[4][64];
    __shared__ int jS[4][64];
    const float sI = s1p[row] + s1p[N_NODES + row]
                   + s1p[2 * N_NODES + row] + s1p[3 * N_NODES + row];
    int j = 0;
    float ev = -1e30f;
    if (lane < deg) {
        j = cols[(size_t)row * MAXDEG + lane];
        float tj = t1p[j] + t1p[N_NODES + j]
                 + t1p[2 * N_NODES + j] + t1p[3 * N_NODES + j];
        float z = sI + tj;
        ev = z > 0.0f ? z : ALPHA * z;
    }
    float m = ev;
    #pragma unroll
    for (int off = 32; off > 0; off >>= 1) m = fmaxf(m, __shfl_xor(m, off));
    float ex = (lane < deg) ? __expf(ev - m) : 0.0f;
    float sum = ex;
    #pragma unroll
    for (int off = 32; off > 0; off >>= 1) sum += __shfl_xor(sum, off);
    pS[wid][lane] = ex / sum;
    jS[wid][lane] = j;
    __syncthreads();

    float acc[4] = {};
    const size_t lo = (size_t)lane * 4;
    int d = 0;
    for (; d + 4 <= deg; d += 4) {
        float p0 = pS[wid][d],     p1 = pS[wid][d + 1];
        float p2 = pS[wid][d + 2], p3 = pS[wid][d + 3];
        f16x4 v0 = *(const f16x4*)(Wh + (size_t)jS[wid][d] * F_HID + lo);
        f16x4 v1 = *(const f16x4*)(Wh + (size_t)jS[wid][d + 1] * F_HID + lo);
        f16x4 v2 = *(const f16x4*)(Wh + (size_t)jS[wid][d + 2] * F_HID + lo);
        f16x4 v3 = *(const f16x4*)(Wh + (size_t)jS[wid][d + 3] * F_HID + lo);
        #pragma unroll
        for (int jj = 0; jj < 4; ++jj)
            acc[jj] += p0 * (float)v0[jj] + p1 * (float)v1[jj]
                     + p2 * (float)v2[jj] + p3 * (float)v3[jj];
    }
    for (; d < deg; ++d) {
        float p = pS[wid][d];
        f16x4 w = *(const f16x4*)(Wh + (size_t)jS[wid][d] * F_HID + lo);
        #pragma unroll
        for (int jj = 0; jj < 4; ++jj) acc[jj] += p * (float)w[jj];
    }
    f32x4 o; f16x4 h;
    #pragma unroll
    for (int jj = 0; jj < 4; ++jj) {
        float v = acc[jj];
        float e = v > 0.0f ? v : (__expf(v) - 1.0f);
        o[jj] = e; h[jj] = (_Float16)e;
    }
    __builtin_nontemporal_store(o, (f32x4*)(enc + (size_t)row * F_HID + lo));
    *(f16x4*)(enc16 + (size_t)row * F_HID + lo) = h;

    f32x4 ws = *(const f32x4*)(w2s + lo);
    f32x4 wt = *(const f32x4*)(w2t + lo);
    float ps = 0.f, pt = 0.f;
    #pragma unroll
    for (int jj = 0; jj < 4; ++jj) { ps += o[jj] * ws[jj]; pt += o[jj] * wt[jj]; }
    #pragma unroll
    for (int off = 32; off > 0; off >>= 1) {
        ps += __shfl_xor(ps, off);
        pt += __shfl_xor(pt, off);
    }
    if (lane == 0) { s2[row] = ps; t2[row] = pt; }
}

// ---------------------------------------------------------------------------
// Kernel C: layer-2 pre-aggregate (linearity): aggE = att2 @ enc (fp16).
// ---------------------------------------------------------------------------
__global__ __launch_bounds__(256)
void aggregate_l2pre(const _Float16* __restrict__ enc16,
                     const int* __restrict__ cols, const int* __restrict__ cnt,
                     const float* __restrict__ s, const float* __restrict__ t,
                     _Float16* __restrict__ aggE16) {
    const int wid = threadIdx.x >> 6, lane = threadIdx.x & 63;
    const int row = blockIdx.x * 4 + wid;
    const int deg = cnt[row];
    __shared__ float pS[4][64];
    __shared__ int jS[4][64];
    int j = 0;
    float ev = -1e30f;
    if (lane < deg) {
        j = cols[(size_t)row * MAXDEG + lane];
        float z = s[row] + t[j];
        ev = z > 0.0f ? z : ALPHA * z;
    }
    float m = ev;
    #pragma unroll
    for (int off = 32; off > 0; off >>= 1) m = fmaxf(m, __shfl_xor(m, off));
    float ex = (lane < deg) ? __expf(ev - m) : 0.0f;
    float sum = ex;
    #pragma unroll
    for (int off = 32; off > 0; off >>= 1) sum += __shfl_xor(sum, off);
    pS[wid][lane] = ex / sum;
    jS[wid][lane] = j;
    __syncthreads();

    float acc[4] = {};
    const size_t lo = (size_t)lane * 4;
    int d = 0;
    for (; d + 4 <= deg; d += 4) {
        float p0 = pS[wid][d],     p1 = pS[wid][d + 1];
        float p2 = pS[wid][d + 2], p3 = pS[wid][d + 3];
        f16x4 v0 = *(const f16x4*)(enc16 + (size_t)jS[wid][d] * F_HID + lo);
        f16x4 v1 = *(const f16x4*)(enc16 + (size_t)jS[wid][d + 1] * F_HID + lo);
        f16x4 v2 = *(const f16x4*)(enc16 + (size_t)jS[wid][d + 2] * F_HID + lo);
        f16x4 v3 = *(const f16x4*)(enc16 + (size_t)jS[wid][d + 3] * F_HID + lo);
        #pragma unroll
        for (int jj = 0; jj < 4; ++jj)
            acc[jj] += p0 * (float)v0[jj] + p1 * (float)v1[jj]
                     + p2 * (float)v2[jj] + p3 * (float)v3[jj];
    }
    for (; d < deg; ++d) {
        float p = pS[wid][d];
        f16x4 w = *(const f16x4*)(enc16 + (size_t)jS[wid][d] * F_HID + lo);
        #pragma unroll
        for (int jj = 0; jj < 4; ++jj) acc[jj] += p * (float)w[jj];
    }
    f16x4 h;
    #pragma unroll
    for (int jj = 0; jj < 4; ++jj) h[jj] = (_Float16)acc[jj];
    *(f16x4*)(aggE16 + (size_t)row * F_HID + lo) = h;
}

// ---------------------------------------------------------------------------
// Kernel D: dec[8192,512] f32 = elu( aggE16[8192,256] @ W2 ). BM=128, BN=64,
// B panel resident in LDS; ELU fused; NT f32 stores.
// ---------------------------------------------------------------------------
__global__ __launch_bounds__(256)
void gemm2e(const _Float16* __restrict__ A, const _Float16* __restrict__ BT,
            float* __restrict__ C) {
    const int LDT = 72, LDB = 264;
    __shared__ _Float16 As[128 * LDT];
    __shared__ _Float16 Bs[64 * LDB];
    const int tid = threadIdx.x;
    const int wid = tid >> 6, lane = tid & 63;
    const int brow = (blockIdx.x >> 3) * 128;
    const int bcol = (blockIdx.x & 7) * 64;
    const int wr = (wid >> 1) * 64, wc = (wid & 1) * 32;

    #pragma unroll
    for (int i = 0; i < 8; ++i) {
        int id = tid + i * 256;
        int r = id >> 5, kc = (id & 31) * 8;
        *(f16x8*)&Bs[r * LDB + kc] = *(const f16x8*)&BT[(size_t)(bcol + r) * F_HID + kc];
    }

    f32x4 acc[4][2];
    #pragma unroll
    for (int m = 0; m < 4; ++m)
        #pragma unroll
        for (int n = 0; n < 2; ++n) acc[m][n] = f32x4{0.f, 0.f, 0.f, 0.f};

    for (int k0 = 0; k0 < F_HID; k0 += 64) {
        #pragma unroll
        for (int i = 0; i < 4; ++i) {
            int id = tid + i * 256;
            int r = id >> 3, kc = (id & 7) * 8;
            *(f16x8*)&As[r * LDT + kc] = *(const f16x8*)&A[(size_t)(brow + r) * F_HID + k0 + kc];
        }
        __syncthreads();
        #pragma unroll
        for (int ks = 0; ks < 2; ++ks) {
            const int kb = ks * 32 + (lane >> 4) * 8;
            f16x8 af[4], bfr[2];
            #pragma unroll
            for (int m = 0; m < 4; ++m)
                af[m] = *(const f16x8*)&As[(wr + m * 16 + (lane & 15)) * LDT + kb];
            #pragma unroll
            for (int n = 0; n < 2; ++n)
                bfr[n] = *(const f16x8*)&Bs[(wc + n * 16 + (lane & 15)) * LDB + k0 + kb];
            #pragma unroll
            for (int m = 0; m < 4; ++m)
                #pragma unroll
                for (int n = 0; n < 2; ++n)
                    acc[m][n] = __builtin_amdgcn_mfma_f32_16x16x32_f16(
                        af[m], bfr[n], acc[m][n], 0, 0, 0);
        }
        __syncthreads();
    }
    #pragma unroll
    for (int m = 0; m < 4; ++m)
        #pragma unroll
        for (int n = 0; n < 2; ++n) {
            int row = brow + wr + m * 16 + ((lane >> 4) << 2);
            int col = bcol + wc + n * 16 + (lane & 15);
            #pragma unroll
            for (int j = 0; j < 4; ++j) {
                float v = acc[m][n][j];
                float e = v > 0.0f ? v : (__expf(v) - 1.0f);
                __builtin_nontemporal_store(e, &C[(size_t)(row + j) * F_IN + col]);
            }
        }
}

// ---------------------------------------------------------------------------
extern "C" void kernel_launch(void* const* d_in, const int* in_sizes, int n_in,
                              void* d_out, int out_size, void* d_ws, size_t ws_size,
                              hipStream_t stream) {
    (void)in_sizes; (void)n_in; (void)out_size; (void)ws_size;
    const float* x   = (const float*)d_in[0];
    const float* adj = (const float*)d_in[1];
    const float* W1  = (const float*)d_in[2];
    const float* a1  = (const float*)d_in[3];
    const float* W2  = (const float*)d_in[4];
    const float* a2  = (const float*)d_in[5];

    float* dec = (float*)d_out;                           // [8192, 512] f32
    float* enc = dec + (size_t)N_NODES * F_IN;            // [8192, 256] f32

    int*      cols   = (int*)d_ws;                        // 8192*64
    int*      cnt    = cols + (size_t)N_NODES * MAXDEG;   // 8192
    float*    s1p    = (float*)(cnt + N_NODES);           // 4*8192 (parts)
    float*    t1p    = s1p + 4 * N_NODES;                 // 4*8192 (parts)
    float*    s2     = t1p + 4 * N_NODES;                 // 8192
    float*    t2     = s2 + N_NODES;                      // 8192
    float*    w2s    = t2 + N_NODES;                      // 256
    float*    w2t    = w2s + F_HID;                       // 256
    _Float16* Wh1    = (_Float16*)(w2t + F_HID);          // 8192*256 fp16
    _Float16* enc16  = Wh1 + (size_t)N_NODES * F_HID;     // 8192*256 fp16
    _Float16* aggE16 = enc16 + (size_t)N_NODES * F_HID;   // 8192*256 fp16
    _Float16* W2T    = aggE16 + (size_t)N_NODES * F_HID;  // 512*256 fp16

    // A. csr (all rows) || gemm1 (direct-W1 staging) || W2T/w2vec prep
    front_kernel<<<2436, 256, 0, stream>>>(adj, cols, cnt, x, W1, a1, Wh1,
                                           s1p, t1p, W2, a2, W2T, w2s, w2t);

    // B. layer-1 attention -> enc, enc16; epilogue s2/t2
    aggregate_l1<<<N_NODES / 4, 256, 0, stream>>>(Wh1, cols, cnt, s1p, t1p,
                                                  w2s, w2t, enc, enc16, s2, t2);

    // C. layer-2 aggregate in input space: aggE = att2 @ enc
    aggregate_l2pre<<<N_NODES / 4, 256, 0, stream>>>(enc16, cols, cnt, s2, t2, aggE16);

    // D. dec = elu(aggE @ W2)
    gemm2e<<<512, 256, 0, stream>>>(aggE16, W2T, dec);
}